// Round 7
// baseline (465.031 us; speedup 1.0000x reference)
//
#include <hip/hip_runtime.h>
#include <hip/hip_bf16.h>

#define JOINTS   22
#define SEQ      176
#define DIN      128
#define NHEAD    8
#define HD       64
#define DMODEL   512
#define NMT      11

typedef __bf16 bf16x8 __attribute__((ext_vector_type(8)));
typedef float  f32x4  __attribute__((ext_vector_type(4)));

__device__ __forceinline__ unsigned short f2bf(float f) {
  __hip_bfloat16 h = __float2bfloat16(f);
  return __builtin_bit_cast(unsigned short, h);
}
__device__ __forceinline__ float bf2f(unsigned short u) {
  __hip_bfloat16 h = __builtin_bit_cast(__hip_bfloat16, u);
  return __bfloat162float(h);
}

// ---------------- workspace layout (ushort elements) ----------------
#define WT_E    0u            // [3][512][128] bf16  W^T (Wq pre-scaled 0.125)
#define BIAS_E  196608u       // [3][512] bf16       (bq pre-scaled)
#define Q_E     198144u       // [4096][176][64] bf16
#define PERQKV  46137344u
#define K_E     (Q_E + PERQKV)
#define V_E     (K_E + PERQKV)   // [4096][64][176] bf16 (transposed, ReLU'd)
#define WS_NEED ((size_t)(V_E + PERQKV) * 2)

// ================== kernel 0: W transpose + bias prep ==================
__global__ __launch_bounds__(256) void prep_kernel(
    const float* __restrict__ Wq, const float* __restrict__ bq,
    const float* __restrict__ Wk, const float* __restrict__ bk,
    const float* __restrict__ Wv, const float* __restrict__ bv,
    unsigned short* __restrict__ ws)
{
  int idx = blockIdx.x * 256 + threadIdx.x;        // < 196608
  int which = idx >> 16;                           // 0..2
  int rem = idx & 65535;
  int n = rem >> 7, k = rem & 127;
  const float* W = (which == 0) ? Wq : (which == 1 ? Wk : Wv);
  float scale = (which == 0) ? 0.125f : 1.0f;
  ws[WT_E + idx] = f2bf(W[k * DMODEL + n] * scale);
  if (idx < 1536) {
    int w2 = idx >> 9, n2 = idx & 511;
    const float* bb = (w2 == 0) ? bq : (w2 == 1 ? bk : bv);
    float s2 = (w2 == 0) ? 0.125f : 1.0f;
    ws[BIAS_E + idx] = f2bf(bb[n2] * s2);
  }
}

// ================== kernel A: QKV projection GEMM ==================
// grid (704 m-blocks, 4 n-blocks), 256 threads. Tile 128x128, K=128.
// Epilogue v2: operand roles chosen per-matrix so the 4 r-regs are the
// contiguous store axis -> packed uint2 stores, /176 hoisted.
__global__ __launch_bounds__(256) void qkv_gemm_kernel(
    const float* __restrict__ x, unsigned short* __restrict__ ws)
{
  __shared__ unsigned short Xs[128 * 136];
  __shared__ unsigned short Wt[128 * 136];
  const int tid  = threadIdx.x;
  const int lane = tid & 63, wave = tid >> 6;
  const int l15  = lane & 15, quad = lane >> 4;
  const int m0 = blockIdx.x * 128;
  const int nb = blockIdx.y;                        // 0..3
  const int wm = (wave >> 1) * 64, wn = (wave & 1) * 64;

  // stage X tile fp32 -> bf16 (coalesced float4)
  {
    const float4* x4 = reinterpret_cast<const float4*>(x + (size_t)m0 * DIN);
    #pragma unroll
    for (int i = 0; i < 16; ++i) {
      int c = tid + i * 256;                        // < 4096
      int row = c >> 5, col4 = c & 31;
      float4 v = x4[c];
      uint2 pk;
      pk.x = (unsigned)f2bf(v.x) | ((unsigned)f2bf(v.y) << 16);
      pk.y = (unsigned)f2bf(v.z) | ((unsigned)f2bf(v.w) << 16);
      *reinterpret_cast<uint2*>(&Xs[row * 136 + col4 * 4]) = pk;
    }
  }

  // ---- store geometry, hoisted (4-aligned groups never cross a 176 line)
  int gb[4], gs[4];   // Q/K: X-row per mt at column l15
  int vb[4], vs[4];   // V:   X-row group per mt at quad*4
  #pragma unroll
  for (int mt = 0; mt < 4; ++mt) {
    int g = m0 + wm + mt * 16 + l15;
    gb[mt] = g / 176; gs[mt] = g - gb[mt] * 176;
    int g0 = m0 + wm + mt * 16 + quad * 4;
    vb[mt] = g0 / 176; vs[mt] = g0 - vb[mt] * 176;
  }

  for (int which = 0; which < 3; ++which) {
    __syncthreads();     // protect Wt from prior-iter readers (also covers Xs)
    {
      const uint4* wsrc = reinterpret_cast<const uint4*>(
          ws + WT_E + which * 65536 + nb * 128 * 128);
      #pragma unroll
      for (int i = 0; i < 8; ++i) {
        int c = tid + i * 256;                      // < 2048
        int row = c >> 4, col8 = c & 15;
        *reinterpret_cast<uint4*>(&Wt[row * 136 + col8 * 8]) = wsrc[c];
      }
    }
    __syncthreads();

    f32x4 acc[16];
    #pragma unroll
    for (int i = 0; i < 16; ++i) acc[i] = (f32x4){0.f, 0.f, 0.f, 0.f};

    #pragma unroll
    for (int kk = 0; kk < 4; ++kk) {
      bf16x8 a[4], bfr[4];
      #pragma unroll
      for (int mt = 0; mt < 4; ++mt)
        a[mt] = *reinterpret_cast<const bf16x8*>(
            &Xs[(wm + mt * 16 + l15) * 136 + kk * 32 + quad * 8]);
      #pragma unroll
      for (int nt = 0; nt < 4; ++nt)
        bfr[nt] = *reinterpret_cast<const bf16x8*>(
            &Wt[(wn + nt * 16 + l15) * 136 + kk * 32 + quad * 8]);
      if (which != 2) {   // Q/K swapped: r-index <-> W channel (store axis d)
        #pragma unroll
        for (int mt = 0; mt < 4; ++mt)
          #pragma unroll
          for (int nt = 0; nt < 4; ++nt)
            acc[mt * 4 + nt] = __builtin_amdgcn_mfma_f32_16x16x32_bf16(
                bfr[nt], a[mt], acc[mt * 4 + nt], 0, 0, 0);
      } else {            // V unswapped: r-index <-> X row (store axis s)
        #pragma unroll
        for (int mt = 0; mt < 4; ++mt)
          #pragma unroll
          for (int nt = 0; nt < 4; ++nt)
            acc[mt * 4 + nt] = __builtin_amdgcn_mfma_f32_16x16x32_bf16(
                a[mt], bfr[nt], acc[mt * 4 + nt], 0, 0, 0);
      }
    }

    if (which != 2) {      // Q / K: store [BH][S][64], packed d-quads
      unsigned short* dst = ws + ((which == 0) ? Q_E : K_E);
      #pragma unroll
      for (int nt = 0; nt < 4; ++nt) {
        int c0 = nb * 128 + wn + nt * 16 + quad * 4;   // 4 consecutive channels
        int h = c0 >> 6, d0 = c0 & 63;
        uint2 bpk = *reinterpret_cast<const uint2*>(
            ws + BIAS_E + which * 512 + c0);
        float b0 = bf2f((unsigned short)(bpk.x & 0xffffu));
        float b1 = bf2f((unsigned short)(bpk.x >> 16));
        float b2 = bf2f((unsigned short)(bpk.y & 0xffffu));
        float b3 = bf2f((unsigned short)(bpk.y >> 16));
        #pragma unroll
        for (int mt = 0; mt < 4; ++mt) {
          f32x4 ac = acc[mt * 4 + nt];
          uint2 pk;
          pk.x = (unsigned)f2bf(ac[0] + b0) | ((unsigned)f2bf(ac[1] + b1) << 16);
          pk.y = (unsigned)f2bf(ac[2] + b2) | ((unsigned)f2bf(ac[3] + b3) << 16);
          *reinterpret_cast<uint2*>(
              &dst[((size_t)(gb[mt] * 8 + h) * 176 + gs[mt]) * 64 + d0]) = pk;
        }
      }
    } else {               // V: ReLU, store transposed [BH][64][S], packed s-quads
      unsigned short* dst = ws + V_E;
      #pragma unroll
      for (int nt = 0; nt < 4; ++nt) {
        int c = nb * 128 + wn + nt * 16 + l15;
        int h = c >> 6, d = c & 63;
        float bs = bf2f(ws[BIAS_E + 1024 + c]);
        #pragma unroll
        for (int mt = 0; mt < 4; ++mt) {
          f32x4 ac = acc[mt * 4 + nt];
          float v0 = fmaxf(ac[0] + bs, 0.f), v1 = fmaxf(ac[1] + bs, 0.f);
          float v2 = fmaxf(ac[2] + bs, 0.f), v3 = fmaxf(ac[3] + bs, 0.f);
          uint2 pk;
          pk.x = (unsigned)f2bf(v0) | ((unsigned)f2bf(v1) << 16);
          pk.y = (unsigned)f2bf(v2) | ((unsigned)f2bf(v3) << 16);
          *reinterpret_cast<uint2*>(
              &dst[((size_t)(vb[mt] * 8 + h) * 64 + d) * 176 + vs[mt]]) = pk;
        }
      }
    }
  }
}

// ================== kernel B: attention v6 (6-wave, register-P) ==========
// 384-thread (6-wave) block per (b,h); same LDS as v5 (48.9 KB -> 3 blk/CU)
// but 18 waves/CU instead of 12. Tiles: mt = wave + 6*i, i in {0,1} -> slots
// 0..11, tile 11 = dummy (wave 5, store-guarded); all waves equal lifetime.
// Per-tile math identical to v5 (proven): swapped QK^T -> lane-local softmax
// -> register-P PV with permuted-k b64 V reads. No Ps buffer.
#define KLD 72     // 144B row stride
#define VLD 184    // 368B row stride

__global__ __launch_bounds__(384, 4) void attn_kernel(
    const unsigned short* __restrict__ ws, float* __restrict__ out)
{
  __shared__ unsigned short Ks[SEQ * KLD];      // 25344 B
  __shared__ unsigned short Vt[HD * VLD];       // 23552 B  (48896 B total)

  const int tid  = threadIdx.x;
  const int lane = tid & 63, wave = tid >> 6;   // wave 0..5
  const int l15  = lane & 15, quad = lane >> 4;
  const int bh = blockIdx.x;
  const int b = bh >> 3, h = bh & 7;

  const unsigned short* qp = ws + Q_E + (size_t)bh * 11264;
  const unsigned short* kp = ws + K_E + (size_t)bh * 11264;
  const unsigned short* vp = ws + V_E + (size_t)bh * 11264;

  // ---- Q prefetch (issues before staging loads; consumed after barrier).
  // mt may be 11 (wave 5 dummy): reads land in adjacent ws regions - safe.
  bf16x8 aq[2][2];
  #pragma unroll
  for (int i = 0; i < 2; ++i) {
    int mt = wave + 6 * i;
    aq[i][0] = *reinterpret_cast<const bf16x8*>(qp + (mt * 16 + l15) * 64 + quad * 8);
    aq[i][1] = *reinterpret_cast<const bf16x8*>(qp + (mt * 16 + l15) * 64 + 32 + quad * 8);
  }

  // ---- stage K: 176 rows x 8 uint4 chunks = 1408
  {
    const uint4* ks4 = reinterpret_cast<const uint4*>(kp);
    #pragma unroll
    for (int i = 0; i < 4; ++i) {
      int c = tid + i * 384;
      if (c < 1408) {
        int row = c >> 3, col = c & 7;
        *reinterpret_cast<uint4*>(&Ks[row * KLD + col * 8]) = ks4[c];
      }
    }
  }
  // ---- stage V^T: 64 rows x 22 uint4 chunks = 1408
  {
    const uint4* vs4 = reinterpret_cast<const uint4*>(vp);
    #pragma unroll
    for (int i = 0; i < 4; ++i) {
      int c = tid + i * 384;
      if (c < 1408) {
        int row = c / 22, col = c - row * 22;
        *reinterpret_cast<uint4*>(&Vt[row * VLD + col * 8]) = vs4[c];
      }
    }
  }
  __syncthreads();

  #pragma unroll
  for (int i = 0; i < 2; ++i) {
    const int mt = wave + 6 * i;          // 0..11 (11 = dummy, stores guarded)

    // ---- QK^T, swapped: A = K rows (k), B = Q rows (q).
    // sc[nt] lane (l15,quad): S[q=mt*16+l15][k=nt*16+quad*4+r]
    f32x4 sc[NMT];
    #pragma unroll
    for (int nt = 0; nt < NMT; ++nt) {
      bf16x8 k0 = *reinterpret_cast<const bf16x8*>(
          &Ks[(nt * 16 + l15) * KLD + quad * 8]);
      bf16x8 k1 = *reinterpret_cast<const bf16x8*>(
          &Ks[(nt * 16 + l15) * KLD + 32 + quad * 8]);
      f32x4 acc = {0.f, 0.f, 0.f, 0.f};
      acc = __builtin_amdgcn_mfma_f32_16x16x32_bf16(k0, aq[i][0], acc, 0, 0, 0);
      acc = __builtin_amdgcn_mfma_f32_16x16x32_bf16(k1, aq[i][1], acc, 0, 0, 0);
      sc[nt] = acc;
    }

    // ---- lane-local masked softmax over its own q row (q = mt*16+l15)
    const int q  = mt * 16 + l15;
    const int lo = (q / JOINTS) * JOINTS;     // frame start
    const int hi = lo + JOINTS;

    float mx0 = -3.0e38f, mx1 = -3.0e38f, mx2 = -3.0e38f, mx3 = -3.0e38f;
    #pragma unroll
    for (int nt = 0; nt < NMT; ++nt) {
      #pragma unroll
      for (int r = 0; r < 4; ++r) {
        int k = nt * 16 + quad * 4 + r;
        bool msk = (k >= lo) && (k < hi) && (k != q);
        float v = msk ? -1.0e30f : sc[nt][r];
        sc[nt][r] = v;
        if (r == 0) mx0 = fmaxf(mx0, v);
        else if (r == 1) mx1 = fmaxf(mx1, v);
        else if (r == 2) mx2 = fmaxf(mx2, v);
        else mx3 = fmaxf(mx3, v);
      }
    }
    float mx = fmaxf(fmaxf(mx0, mx1), fmaxf(mx2, mx3));
    mx = fmaxf(mx, __shfl_xor(mx, 16));
    mx = fmaxf(mx, __shfl_xor(mx, 32));

    float s0 = 0.f, s1 = 0.f, s2 = 0.f, s3 = 0.f;
    #pragma unroll
    for (int nt = 0; nt < NMT; ++nt) {
      float e0 = __expf(sc[nt][0] - mx);
      float e1 = __expf(sc[nt][1] - mx);
      float e2 = __expf(sc[nt][2] - mx);
      float e3 = __expf(sc[nt][3] - mx);
      sc[nt][0] = e0; sc[nt][1] = e1; sc[nt][2] = e2; sc[nt][3] = e3;
      s0 += e0; s1 += e1; s2 += e2; s3 += e3;
    }
    float sum = (s0 + s1) + (s2 + s3);
    sum += __shfl_xor(sum, 16);
    sum += __shfl_xor(sum, 32);
    float rinv = 1.0f / sum;

    // ---- normalize + pack pairs (ntA,ntB) -> A-fragments in natural order
    // af[pr] elems: [P@2pr*16+quad*4+0..3, P@(2pr+1)*16+quad*4+0..3]
    bf16x8 af[6];
    #pragma unroll
    for (int pr = 0; pr < 6; ++pr) {
      const int ntA = 2 * pr, ntB = 2 * pr + 1;
      uint4 a4;
      {
        float p0 = sc[ntA][0] * rinv, p1 = sc[ntA][1] * rinv;
        float p2 = sc[ntA][2] * rinv, p3 = sc[ntA][3] * rinv;
        a4.x = (unsigned)f2bf(p0) | ((unsigned)f2bf(p1) << 16);
        a4.y = (unsigned)f2bf(p2) | ((unsigned)f2bf(p3) << 16);
      }
      if (pr < 5) {
        float p0 = sc[ntB][0] * rinv, p1 = sc[ntB][1] * rinv;
        float p2 = sc[ntB][2] * rinv, p3 = sc[ntB][3] * rinv;
        a4.z = (unsigned)f2bf(p0) | ((unsigned)f2bf(p1) << 16);
        a4.w = (unsigned)f2bf(p2) | ((unsigned)f2bf(p3) << 16);
      } else {
        a4.z = 0u; a4.w = 0u;            // pad half: contributes 0
      }
      af[pr] = __builtin_bit_cast(bf16x8, a4);
    }

    // ---- PV: B-operand read at the SAME permuted k-offsets (two b64)
    #pragma unroll
    for (int nt_o = 0; nt_o < 4; ++nt_o) {
      const unsigned short* vrow = &Vt[(nt_o * 16 + l15) * VLD];
      f32x4 acc = {0.f, 0.f, 0.f, 0.f};
      #pragma unroll
      for (int pr = 0; pr < 6; ++pr) {
        const int ntA = 2 * pr, ntB = 2 * pr + 1;
        uint2 blo = *reinterpret_cast<const uint2*>(vrow + ntA * 16 + quad * 4);
        uint2 bhi = (pr < 5)
            ? *reinterpret_cast<const uint2*>(vrow + ntB * 16 + quad * 4)
            : (uint2){0u, 0u};
        uint4 b4; b4.x = blo.x; b4.y = blo.y; b4.z = bhi.x; b4.w = bhi.y;
        bf16x8 bf = __builtin_bit_cast(bf16x8, b4);
        acc = __builtin_amdgcn_mfma_f32_16x16x32_bf16(af[pr], bf, acc, 0, 0, 0);
      }
      if (mt < NMT) {
        #pragma unroll
        for (int r = 0; r < 4; ++r) {
          int qq = mt * 16 + quad * 4 + r;
          out[((size_t)b * SEQ + qq) * DMODEL + h * HD + nt_o * 16 + l15] =
              acc[r];
        }
      }
    }
  }
}

// ================== fallback: proven round-2 fused kernel ==================
#define BLK      704
#define XS_LD 136
#define WS_LD 136
#define QK_LD 72
#define PV_LD 184

struct __align__(16) SMem {
  union {
    struct {
      unsigned short Xs[SEQ * XS_LD];
      unsigned short Ws[HD  * WS_LD];
    } p1;
    unsigned short Ps[SEQ * PV_LD];
  } u;
  unsigned short Qs[SEQ * QK_LD];
  unsigned short Ks[SEQ * QK_LD];
  unsigned short Vt[HD  * PV_LD];
};

__global__ __launch_bounds__(BLK) void mha_fused_kernel(
    const float* __restrict__ x,
    const float* __restrict__ Wq, const float* __restrict__ bq,
    const float* __restrict__ Wk, const float* __restrict__ bk,
    const float* __restrict__ Wv, const float* __restrict__ bv,
    float* __restrict__ out)
{
  __shared__ SMem sm;
  const int tid  = threadIdx.x;
  const int lane = tid & 63;
  const int wave = tid >> 6;
  const int l15  = lane & 15;
  const int quad = lane >> 4;
  const int b    = blockIdx.x >> 3;
  const int h    = blockIdx.x & 7;

  const uint4 z4 = {0u, 0u, 0u, 0u};
  const bf16x8 zfrag = __builtin_bit_cast(bf16x8, z4);

  {
    const float4* xg = reinterpret_cast<const float4*>(x + (size_t)b * (SEQ * DIN));
    #pragma unroll
    for (int i = 0; i < 8; ++i) {
      int c = tid + i * BLK;
      int row  = c >> 5;
      int col4 = c & 31;
      float4 v = xg[c];
      uint2 pk;
      pk.x = (unsigned)f2bf(v.x) | ((unsigned)f2bf(v.y) << 16);
      pk.y = (unsigned)f2bf(v.z) | ((unsigned)f2bf(v.w) << 16);
      *reinterpret_cast<uint2*>(&sm.u.p1.Xs[row * XS_LD + col4 * 4]) = pk;
    }
  }

  const float* Wptr[3] = {Wq, Wk, Wv};
  const float* Bptr[3] = {bq, bk, bv};

  for (int m = 0; m < 3; ++m) {
    for (int k = wave; k < DIN; k += NMT)
      sm.u.p1.Ws[lane * WS_LD + k] = f2bf(Wptr[m][(size_t)k * DMODEL + h * HD + lane]);
    __syncthreads();

    const int mt = wave;
    bf16x8 a[4];
    #pragma unroll
    for (int kk = 0; kk < 4; ++kk)
      a[kk] = *reinterpret_cast<const bf16x8*>(
          &sm.u.p1.Xs[(mt * 16 + l15) * XS_LD + kk * 32 + quad * 8]);

    #pragma unroll
    for (int nt = 0; nt < 4; ++nt) {
      f32x4 acc = {0.f, 0.f, 0.f, 0.f};
      #pragma unroll
      for (int kk = 0; kk < 4; ++kk) {
        bf16x8 bb = *reinterpret_cast<const bf16x8*>(
            &sm.u.p1.Ws[(nt * 16 + l15) * WS_LD + kk * 32 + quad * 8]);
        acc = __builtin_amdgcn_mfma_f32_16x16x32_bf16(a[kk], bb, acc, 0, 0, 0);
      }
      float bs = Bptr[m][h * HD + nt * 16 + l15];
      if (m == 0) {
        #pragma unroll
        for (int r = 0; r < 4; ++r)
          sm.Qs[(mt * 16 + quad * 4 + r) * QK_LD + nt * 16 + l15] =
              f2bf((acc[r] + bs) * 0.125f);
      } else if (m == 1) {
        #pragma unroll
        for (int r = 0; r < 4; ++r)
          sm.Ks[(mt * 16 + quad * 4 + r) * QK_LD + nt * 16 + l15] =
              f2bf(acc[r] + bs);
      } else {
        float v0 = fmaxf(acc[0] + bs, 0.f), v1 = fmaxf(acc[1] + bs, 0.f);
        float v2 = fmaxf(acc[2] + bs, 0.f), v3 = fmaxf(acc[3] + bs, 0.f);
        uint2 pk;
        pk.x = (unsigned)f2bf(v0) | ((unsigned)f2bf(v1) << 16);
        pk.y = (unsigned)f2bf(v2) | ((unsigned)f2bf(v3) << 16);
        *reinterpret_cast<uint2*>(
            &sm.Vt[(nt * 16 + l15) * PV_LD + mt * 16 + quad * 4]) = pk;
      }
    }
    __syncthreads();
  }

  {
    const int mt = wave;
    bf16x8 aq0 = *reinterpret_cast<const bf16x8*>(
        &sm.Qs[(mt * 16 + l15) * QK_LD + 0 + quad * 8]);
    bf16x8 aq1 = *reinterpret_cast<const bf16x8*>(
        &sm.Qs[(mt * 16 + l15) * QK_LD + 32 + quad * 8]);

    f32x4 sc[NMT];
    #pragma unroll
    for (int nt = 0; nt < NMT; ++nt) {
      f32x4 acc = {0.f, 0.f, 0.f, 0.f};
      bf16x8 k0 = *reinterpret_cast<const bf16x8*>(
          &sm.Ks[(nt * 16 + l15) * QK_LD + 0 + quad * 8]);
      bf16x8 k1 = *reinterpret_cast<const bf16x8*>(
          &sm.Ks[(nt * 16 + l15) * QK_LD + 32 + quad * 8]);
      acc = __builtin_amdgcn_mfma_f32_16x16x32_bf16(aq0, k0, acc, 0, 0, 0);
      acc = __builtin_amdgcn_mfma_f32_16x16x32_bf16(aq1, k1, acc, 0, 0, 0);
      sc[nt] = acc;
    }

    float rinv[4];
    #pragma unroll
    for (int r = 0; r < 4; ++r) {
      const int q  = mt * 16 + quad * 4 + r;
      const int fq = q / JOINTS;
      float mx = -3.0e38f;
      #pragma unroll
      for (int nt = 0; nt < NMT; ++nt) {
        int c = nt * 16 + l15;
        bool masked = ((c / JOINTS) == fq) && (c != q);
        float v = masked ? -1.0e30f : sc[nt][r];
        sc[nt][r] = v;
        mx = fmaxf(mx, v);
      }
      mx = fmaxf(mx, __shfl_xor(mx, 1));
      mx = fmaxf(mx, __shfl_xor(mx, 2));
      mx = fmaxf(mx, __shfl_xor(mx, 4));
      mx = fmaxf(mx, __shfl_xor(mx, 8));
      float sum = 0.f;
      #pragma unroll
      for (int nt = 0; nt < NMT; ++nt) {
        float e = __expf(sc[nt][r] - mx);
        sum += e;
        sm.u.Ps[q * PV_LD + nt * 16 + l15] = f2bf(e);
      }
      sum += __shfl_xor(sum, 1);
      sum += __shfl_xor(sum, 2);
      sum += __shfl_xor(sum, 4);
      sum += __shfl_xor(sum, 8);
      rinv[r] = 1.0f / sum;
    }

    #pragma unroll
    for (int nt = 0; nt < 4; ++nt) {
      f32x4 acc = {0.f, 0.f, 0.f, 0.f};
      #pragma unroll
      for (int kk = 0; kk < 6; ++kk) {
        bool act = (kk < 5) || (quad < 2);
        int off = act ? (kk * 32 + quad * 8) : 0;
        bf16x8 ap  = *reinterpret_cast<const bf16x8*>(
            &sm.u.Ps[(mt * 16 + l15) * PV_LD + off]);
        bf16x8 bv8 = *reinterpret_cast<const bf16x8*>(
            &sm.Vt[(nt * 16 + l15) * PV_LD + off]);
        if (!act) { ap = zfrag; bv8 = zfrag; }
        acc = __builtin_amdgcn_mfma_f32_16x16x32_bf16(ap, bv8, acc, 0, 0, 0);
      }
      #pragma unroll
      for (int r = 0; r < 4; ++r) {
        int q = mt * 16 + quad * 4 + r;
        out[((size_t)b * SEQ + q) * DMODEL + h * HD + nt * 16 + l15] =
            acc[r] * rinv[r];
      }
    }
  }
}

// ================== launch ==================
extern "C" void kernel_launch(void* const* d_in, const int* in_sizes, int n_in,
                              void* d_out, int out_size, void* d_ws, size_t ws_size,
                              hipStream_t stream) {
  const float* x  = (const float*)d_in[0];
  const float* Wq = (const float*)d_in[1];
  const float* bq = (const float*)d_in[2];
  const float* Wk = (const float*)d_in[3];
  const float* bk = (const float*)d_in[4];
  const float* Wv = (const float*)d_in[5];
  const float* bv = (const float*)d_in[6];
  const int B = in_sizes[0] / (SEQ * DIN);   // 512

  if (ws_size >= WS_NEED && B == 512) {
    unsigned short* ws = (unsigned short*)d_ws;
    hipLaunchKernelGGL(prep_kernel, dim3(768), dim3(256), 0, stream,
                       Wq, bq, Wk, bk, Wv, bv, ws);
    hipLaunchKernelGGL(qkv_gemm_kernel, dim3(704, 4), dim3(256), 0, stream,
                       x, ws);
    hipLaunchKernelGGL(attn_kernel, dim3(4096), dim3(384), 0, stream,
                       (const unsigned short*)ws, (float*)d_out);
  } else {
    hipLaunchKernelGGL(mha_fused_kernel, dim3(B * NHEAD), dim3(BLK), 0, stream,
                       x, Wq, bq, Wk, bk, Wv, bv, (float*)d_out);
  }
}